// Round 9
// baseline (110.989 us; speedup 1.0000x reference)
//
#include <hip/hip_runtime.h>

typedef __bf16 bf16x8 __attribute__((ext_vector_type(8)));
typedef float  f32x4  __attribute__((ext_vector_type(4)));
typedef unsigned short u16;

#define NB    512
#define SEQ   128
#define EMB   300
#define NT_TOT 19               // N = 304 unified (300 filters padded), tiles of 16
#define KT_TOT 50               // K = 1600 = 50*32
#define WU_ELEMS (304 * 1600)   // 486400 bf16
#define OFF_FEATS (WU_ELEMS * 2)

// LDS: A tile (132 rows x 320 bf16, 640B stride) + 4 wave-private B dbuf regions
#define A_BYTES (132 * 640)     // 84480
// wave (wm,wn): NTW = 10 (wn0) / 9 (wn1); region per wm = 2x10KB + 2x9KB = 38912
#define B_REGION_WM 38912
#define LDS_TOTAL (A_BYTES + 2 * B_REGION_WM)   // 162304 <= 163840

// async global->LDS, 16B/lane; LDS dest = wave-uniform base (HW adds lane*16)
#define GLOAD16(gsrc, ldst)                                                    \
  __builtin_amdgcn_global_load_lds(                                            \
      (const __attribute__((address_space(1))) unsigned int*)(gsrc),           \
      (__attribute__((address_space(3))) unsigned int*)(ldst), 16, 0, 0)

__device__ __forceinline__ u16 f2bf(float f) {
  unsigned u = __builtin_bit_cast(unsigned, f);
  return (u16)((u + 0x7fffu + ((u >> 16) & 1u)) >> 16);   // RNE
}

// Unified weights, MFMA-B-fragment order, kt-major (r4/r6/r8-verified):
//   elem idx = ((kt*19 + nt)*64 + lane)*8 + j
//   -> W[f = nt*16 + (lane&15)][kk = kt*32 + (lane>>4)*8 + j]
// kk -> (dk = kk/320, e = kk%320); k=5-aligned window (x rows s-2..s+2):
//   f<100: w3 valid dk 2..4 ; f<200: w4 valid dk 1..4 ; f<300: w5 dk 0..4
__global__ void prep_weights(const float* __restrict__ w3, const float* __restrict__ w4,
                             const float* __restrict__ w5, u16* __restrict__ wu) {
  int idx = blockIdx.x * blockDim.x + threadIdx.x;
  if (idx >= WU_ELEMS) return;
  int j = idx & 7, l = (idx >> 3) & 63, t = idx >> 9;
  int nt = t % NT_TOT, kt = t / NT_TOT;
  int f  = nt * 16 + (l & 15);
  int kk = kt * 32 + ((l >> 4) << 3) + j;
  int dk = kk / 320, e = kk - dk * 320;
  float v = 0.f;
  if (f < 300 && e < 300) {
    if (f < 100)      { if (dk >= 2) v = w3[(f * 3 + dk - 2) * 300 + e]; }
    else if (f < 200) { if (dk >= 1) v = w4[((f - 100) * 4 + dk - 1) * 300 + e]; }
    else              {              v = w5[((f - 200) * 5 + dk) * 300 + e]; }
  }
  wu[idx] = f2bf(v);
}

// r8's race-free barrier-free pipeline, register blocking doubled: wave = 4M x NTW N
// (40/36 MFMA per K-step), ONE wave per SIMD. Two named fragment sets (C,N):
// per kt: lgkm-fence -> STAGE G(kt+2) -> vmcnt(NTW) -> prefetch frags(kt+1) -> MFMA(kt).
template<int NTW>
__device__ __forceinline__ void kloop_epi(const char* smem, const char* wB, char* myslot,
                                          int wm, int ntb, int l, int b,
                                          const float* __restrict__ b3,
                                          const float* __restrict__ b4,
                                          const float* __restrict__ b5,
                                          float* __restrict__ feats) {
  const int lo = l & 15, hi = l >> 4;
  const int wmbase = wm * 64;

  f32x4 acc[4][NTW];
  #pragma unroll
  for (int mt = 0; mt < 4; ++mt)
    #pragma unroll
    for (int j = 0; j < NTW; ++j) acc[mt][j] = (f32x4){0.f, 0.f, 0.f, 0.f};

  bf16x8 aC[4], bC[NTW], aN[4], bN[NTW];

#define LGKM_FENCE() {                                                         \
    asm volatile("s_waitcnt lgkmcnt(0)" ::: "memory");                         \
    __builtin_amdgcn_sched_barrier(0); }

#define STAGE(KTGT, HALF) {                                                    \
    const char* _g = wB + (size_t)(KTGT) * (NT_TOT * 1024) + ntb * 1024 + l * 16; \
    char* _d = myslot + (HALF) * (NTW * 1024);                                 \
    _Pragma("unroll") for (int j = 0; j < NTW; ++j)                            \
      GLOAD16(_g + j * 1024, _d + j * 1024); }

#define PREFETCH(DK, EG, HALF, AR, BR) {                                       \
    const char* _bs = myslot + (HALF) * (NTW * 1024) + l * 16;                 \
    _Pragma("unroll") for (int j = 0; j < NTW; ++j)                            \
      BR[j] = *reinterpret_cast<const bf16x8*>(_bs + j * 1024);                \
    _Pragma("unroll") for (int mt = 0; mt < 4; ++mt) {                         \
      int _row  = wmbase + mt * 16 + lo + (DK);                                \
      int _boff = (_row * 640 + (EG) * 64 + hi * 16) ^ ((_row & 7) << 4);      \
      AR[mt] = *reinterpret_cast<const bf16x8*>(smem + _boff); } }

#define MF(AR, BR) {                                                           \
    __builtin_amdgcn_s_setprio(1);                                             \
    _Pragma("unroll") for (int mt = 0; mt < 4; ++mt)                           \
    _Pragma("unroll") for (int j = 0; j < NTW; ++j)                            \
      acc[mt][j] = __builtin_amdgcn_mfma_f32_16x16x32_bf16(AR[mt], BR[j],      \
                                                           acc[mt][j], 0, 0, 0); \
    __builtin_amdgcn_s_setprio(0); }

  // prologue: read kt=0 frags (half0, dk=0, eg=0); fence before first overwrite of half0
  PREFETCH(0, 0, 0, aC, bC);
  LGKM_FENCE();

  int dkA = 0, egA = 1;   // prefetch indices for iterA: 1,3,...,47
  int dkB = 0, egB = 2;   // prefetch indices for iterB: 2,4,...,48

  #pragma unroll 1
  for (int kt = 0; kt < 48; kt += 2) {
    // ---- iterA (kt even): MFMA B(kt) from set C ----
    LGKM_FENCE();                                       // half0's ds_reads retired
    STAGE(kt + 2, 0);
    asm volatile("s_waitcnt vmcnt(%0)" :: "i"(NTW) : "memory");  // G(kt+1) landed
    __builtin_amdgcn_sched_barrier(0);
    PREFETCH(dkA, egA, 1, aN, bN);                      // read B(kt+1) / A(kt+1)
    __builtin_amdgcn_sched_barrier(0);
    MF(aC, bC);
    egA += 2; if (egA >= 10) { egA -= 10; ++dkA; }

    // ---- iterB (kt+1 odd): MFMA B(kt+1) from set N ----
    LGKM_FENCE();                                       // half1's ds_reads retired
    STAGE(kt + 3, 1);
    asm volatile("s_waitcnt vmcnt(%0)" :: "i"(NTW) : "memory");  // G(kt+2) landed
    __builtin_amdgcn_sched_barrier(0);
    PREFETCH(dkB, egB, 0, aC, bC);                      // read B(kt+2) / A(kt+2)
    __builtin_amdgcn_sched_barrier(0);
    MF(aN, bN);
    egB += 2; if (egB >= 10) { egB -= 10; ++dkB; }
  }

  // peeled kt=48: MFMA B(48) (set C, half0); prefetch B(49) (half1, dk=4, eg=9)
  asm volatile("s_waitcnt vmcnt(0)" ::: "memory");      // G(49) landed
  __builtin_amdgcn_sched_barrier(0);
  PREFETCH(4, 9, 1, aN, bN);
  __builtin_amdgcn_sched_barrier(0);
  MF(aC, bC);
  // peeled kt=49
  MF(aN, bN);

#undef LGKM_FENCE
#undef STAGE
#undef PREFETCH
#undef MF

  // epilogue: bias + relu + masked max over the sample's 128 s-positions
  #pragma unroll
  for (int j = 0; j < NTW; ++j) {
    int f = (ntb + j) * 16 + lo;
    if (f < 300) {
      float bia  = (f < 100) ? b3[f] : (f < 200) ? b4[f - 100] : b5[f - 200];
      int   sval = (f < 100) ? 126   : (f < 200) ? 127         : 128;
      float cmax = 0.f;                            // relu floor
      #pragma unroll
      for (int mt = 0; mt < 4; ++mt)
        #pragma unroll
        for (int ii = 0; ii < 4; ++ii) {
          int s = wmbase + mt * 16 + hi * 4 + ii;  // C/D: row=(l>>4)*4+ii, col=l&15
          float v = acc[mt][j][ii] + bia;
          if (s < sval) cmax = fmaxf(cmax, v);
        }
      cmax = fmaxf(cmax, __shfl_xor(cmax, 16));
      cmax = fmaxf(cmax, __shfl_xor(cmax, 32));
      if (hi == 0)
        atomicMax((int*)&feats[b * 300 + f], __float_as_int(fmaxf(cmax, 0.f)));
    }
  }
}

// Block = one sample: M=128, N=304, K=1600. 4 waves (wm 0-1 x wn 0-1), wave = 4M x
// 10N/9N -> 40/36 MFMA per K-step, 1 wave/SIMD. A staged once (verified swizzle);
// B wave-private dbuf, barrier-free, r8 race-free fence pattern.
__global__ __launch_bounds__(256, 1)
void conv_max_kernel(const float* __restrict__ x, const u16* __restrict__ wu,
                     const float* __restrict__ b3, const float* __restrict__ b4,
                     const float* __restrict__ b5, float* __restrict__ feats) {
  __shared__ __align__(16) char smem[LDS_TOTAL];
  char* Bs = smem + A_BYTES;

  const int b   = blockIdx.x;
  const int tid = threadIdx.x;
  const int l = tid & 63, w = tid >> 6;
  const int wm = w >> 1, wn = w & 1;
  const int ntw = wn ? 9 : 10;
  const int ntb = wn ? 10 : 0;
  const float* xb = x + (size_t)b * (SEQ * EMB);
  const char*  wB = (const char*)wu;
  char* myslot = Bs + wm * B_REGION_WM + wn * 20480;

  // prologue: stage kt=0 -> half0, kt=1 -> half1 (lands before the A-stage barrier)
  for (int i = 0; i < ntw; ++i) {
    GLOAD16(wB + (0 * NT_TOT + ntb + i) * 1024 + l * 16, myslot + i * 1024);
    GLOAD16(wB + (1 * NT_TOT + ntb + i) * 1024 + l * 16, myslot + (ntw + i) * 1024);
  }

  // stage A: rows -2..129 (132), 640B stride, XOR swizzle (r1/r4-verified, 0 conflicts)
  for (int t = tid; t < 132 * 80; t += 256) {
    int r = t / 80, cg = t - r * 80;
    int xr = r - 2;
    float4 v = make_float4(0.f, 0.f, 0.f, 0.f);
    if (xr >= 0 && xr < SEQ && cg < 75)
      v = *reinterpret_cast<const float4*>(xb + xr * EMB + cg * 4);
    ushort4 h;
    h.x = f2bf(v.x); h.y = f2bf(v.y); h.z = f2bf(v.z); h.w = f2bf(v.w);
    int boff = (r * 640 + cg * 8) ^ ((r & 7) << 4);
    *reinterpret_cast<ushort4*>(smem + boff) = h;
  }
  __syncthreads();   // the ONLY block-wide barrier: A visible, G(0)/G(1) drained

  if (wn) kloop_epi<9> (smem, wB, myslot, wm, 10, l, b, b3, b4, b5, feats);
  else    kloop_epi<10>(smem, wB, myslot, wm,  0, l, b, b3, b4, b5, feats);
}

// feats[512,300] @ Wfc[5,300]^T + bfc -> log_softmax. One wave per row.
__global__ void fc_kernel(const float* __restrict__ feats, const float* __restrict__ Wfc,
                          const float* __restrict__ bfc, float* __restrict__ out) {
  const int b = blockIdx.x, l = threadIdx.x;
  float acc[5] = {0.f, 0.f, 0.f, 0.f, 0.f};
  for (int e = l; e < 300; e += 64) {
    float fv = feats[b * 300 + e];
    #pragma unroll
    for (int c = 0; c < 5; ++c) acc[c] += fv * Wfc[c * 300 + e];
  }
  #pragma unroll
  for (int off = 32; off; off >>= 1) {
    #pragma unroll
    for (int c = 0; c < 5; ++c) acc[c] += __shfl_down(acc[c], off);
  }
  if (l == 0) {
    float lg[5], m = -1e30f;
    #pragma unroll
    for (int c = 0; c < 5; ++c) { lg[c] = acc[c] + bfc[c]; m = fmaxf(m, lg[c]); }
    float se = 0.f;
    #pragma unroll
    for (int c = 0; c < 5; ++c) se += expf(lg[c] - m);
    float ls = logf(se);
    #pragma unroll
    for (int c = 0; c < 5; ++c) out[b * 5 + c] = lg[c] - m - ls;
  }
}

extern "C" void kernel_launch(void* const* d_in, const int* in_sizes, int n_in,
                              void* d_out, int out_size, void* d_ws, size_t ws_size,
                              hipStream_t stream) {
  const float* x   = (const float*)d_in[0];
  const float* w3  = (const float*)d_in[1];
  const float* b3  = (const float*)d_in[2];
  const float* w4  = (const float*)d_in[3];
  const float* b4  = (const float*)d_in[4];
  const float* w5  = (const float*)d_in[5];
  const float* b5  = (const float*)d_in[6];
  const float* Wfc = (const float*)d_in[7];
  const float* bfc = (const float*)d_in[8];
  float* out = (float*)d_out;

  u16*   wu    = (u16*)d_ws;
  float* feats = (float*)((char*)d_ws + OFF_FEATS);

  hipMemsetAsync(feats, 0, NB * 300 * sizeof(float), stream);  // atomicMax target

  prep_weights<<<(WU_ELEMS + 255) / 256, 256, 0, stream>>>(w3, w4, w5, wu);
  conv_max_kernel<<<NB, 256, 0, stream>>>(x, wu, b3, b4, b5, feats);
  fc_kernel<<<NB, 64, 0, stream>>>(feats, Wfc, bfc, out);
}

// Round 10
// 75.828 us; speedup vs baseline: 1.4637x; 1.4637x over previous
//
#include <hip/hip_runtime.h>

typedef __bf16 bf16x8 __attribute__((ext_vector_type(8)));
typedef float  f32x4  __attribute__((ext_vector_type(4)));
typedef unsigned short u16;

#define NB    512
#define SEQ   128
#define EMB   300
#define NT_TOT 19               // N = 304 unified (300 filters padded), tiles of 16
#define KT_TOT 50               // K = 1600 = 50*32
#define KT_BYTES (NT_TOT * 1024)   // 19456 B per K-step of all tiles
#define WU_ELEMS (304 * 1600)   // 486400 bf16
#define OFF_FEATS (WU_ELEMS * 2)

// A tile: 68 rows (+1 guard) x 320 bf16, row stride 656 B (= 164 dwords == 4 mod 32:
// banks rotate 4/row -> uniform 2-lane/bank-group on ds_read_b128, NO swizzle needed,
// so all A addresses are base + compile-time offset immediates).
#define AROW 656
#define A_BYTES (69 * AROW)     // 45264 -> 2 blocks/CU

__device__ __forceinline__ u16 f2bf(float f) {
  unsigned u = __builtin_bit_cast(unsigned, f);
  return (u16)((u + 0x7fffu + ((u >> 16) & 1u)) >> 16);   // RNE
}

// Unified weights, MFMA-B-fragment order, kt-major (r4/r6/r8-verified):
//   elem idx = ((kt*19 + nt)*64 + lane)*8 + j
//   -> W[f = nt*16 + (lane&15)][kk = kt*32 + (lane>>4)*8 + j]
// kk -> (dk = kk/320, e = kk%320); k=5-aligned window (x rows s-2..s+2):
//   f<100: w3 valid dk 2..4 ; f<200: w4 valid dk 1..4 ; f<300: w5 dk 0..4
__global__ void prep_weights(const float* __restrict__ w3, const float* __restrict__ w4,
                             const float* __restrict__ w5, u16* __restrict__ wu) {
  int idx = blockIdx.x * blockDim.x + threadIdx.x;
  if (idx >= WU_ELEMS) return;
  int j = idx & 7, l = (idx >> 3) & 63, t = idx >> 9;
  int nt = t % NT_TOT, kt = t / NT_TOT;
  int f  = nt * 16 + (l & 15);
  int kk = kt * 32 + ((l >> 4) << 3) + j;
  int dk = kk / 320, e = kk - dk * 320;
  float v = 0.f;
  if (f < 300 && e < 300) {
    if (f < 100)      { if (dk >= 2) v = w3[(f * 3 + dk - 2) * 300 + e]; }
    else if (f < 200) { if (dk >= 1) v = w4[((f - 100) * 4 + dk - 1) * 300 + e]; }
    else              {              v = w5[((f - 200) * 5 + dk) * 300 + e]; }
  }
  wu[idx] = f2bf(v);
}

// K-loop: A from LDS (offset-immediate reads, 1-step reg prefetch), B straight
// global->VGPR double-buffered 2 deep. NO LDS writes in loop, NO manual fences --
// all waits are compiler-counted (vmcnt for B regs, lgkmcnt for A regs).
template<int NTW>
__device__ __forceinline__ void kloop_epi(const char* xs, const char* wB,
                                          int ntb, int l, int b, int s0,
                                          const float* __restrict__ b3,
                                          const float* __restrict__ b4,
                                          const float* __restrict__ b5,
                                          float* __restrict__ feats) {
  const int lo = l & 15, hi = l >> 4;

  f32x4 acc[4][NTW];
  #pragma unroll
  for (int mt = 0; mt < 4; ++mt)
    #pragma unroll
    for (int j = 0; j < NTW; ++j) acc[mt][j] = (f32x4){0.f, 0.f, 0.f, 0.f};

  bf16x8 aC[4], aN[4], bC[NTW], bN[NTW];

  // B(0) -> bC, B(1) -> bN; thereafter load B(kt+2) into the just-consumed set.
  const char* gB = wB + ntb * 1024 + l * 16;
  #pragma unroll
  for (int j = 0; j < NTW; ++j) bC[j] = *reinterpret_cast<const bf16x8*>(gB + j * 1024);
  #pragma unroll
  for (int j = 0; j < NTW; ++j) bN[j] = *reinterpret_cast<const bf16x8*>(gB + KT_BYTES + j * 1024);
  gB += 2 * KT_BYTES;

  // A bases for dk=0: row r = mt*16 + lo + dk, addr = r*656 + hi*16 (+ eg*64 imm)
  int abase[4];
  #pragma unroll
  for (int mt = 0; mt < 4; ++mt) abase[mt] = (mt * 16 + lo) * AROW + hi * 16;

  // prologue: read A(kt=0) = (dk0, eg0) into aC
  #pragma unroll
  for (int mt = 0; mt < 4; ++mt)
    aC[mt] = *reinterpret_cast<const bf16x8*>(xs + abase[mt]);

  // Per step: prefetch A(next) -> MFMA(cur) -> load B(kt+2) into consumed B set.
  // eg==9 prefetches (dk+1, eg0) via offset 656 (one extra row stride).
#define STEP(AOFF, Acon, Anex, Bcon) {                                         \
    _Pragma("unroll") for (int mt = 0; mt < 4; ++mt)                           \
      Anex[mt] = *reinterpret_cast<const bf16x8*>(xs + abase[mt] + (AOFF));    \
    __builtin_amdgcn_s_setprio(1);                                             \
    _Pragma("unroll") for (int mt = 0; mt < 4; ++mt)                           \
    _Pragma("unroll") for (int j = 0; j < NTW; ++j)                            \
      acc[mt][j] = __builtin_amdgcn_mfma_f32_16x16x32_bf16(Acon[mt], Bcon[j],  \
                                                           acc[mt][j], 0, 0, 0); \
    __builtin_amdgcn_s_setprio(0);                                             \
    _Pragma("unroll") for (int j = 0; j < NTW; ++j)                            \
      Bcon[j] = *reinterpret_cast<const bf16x8*>(gB + j * 1024);               \
    gB += KT_BYTES; }

  #pragma unroll 1
  for (int dk = 0; dk < 5; ++dk) {
    STEP( 64, aC, aN, bC)   // eg 0
    STEP(128, aN, aC, bN)   // eg 1
    STEP(192, aC, aN, bC)   // eg 2
    STEP(256, aN, aC, bN)   // eg 3
    STEP(320, aC, aN, bC)   // eg 4
    STEP(384, aN, aC, bN)   // eg 5
    STEP(448, aC, aN, bC)   // eg 6
    STEP(512, aN, aC, bN)   // eg 7
    STEP(576, aC, aN, bC)   // eg 8
    STEP(656, aN, aC, bN)   // eg 9: prefetch (dk+1, 0)
    #pragma unroll
    for (int mt = 0; mt < 4; ++mt) abase[mt] += AROW;
  }
  // tail over-reads (B(50),B(51) land in ws feats region; A guard row) are never consumed
#undef STEP

  // epilogue: bias + relu + masked max over this block's 64 s-positions
  #pragma unroll
  for (int j = 0; j < NTW; ++j) {
    int f = (ntb + j) * 16 + lo;
    if (f < 300) {
      float bia  = (f < 100) ? b3[f] : (f < 200) ? b4[f - 100] : b5[f - 200];
      int   sval = (f < 100) ? 126   : (f < 200) ? 127         : 128;
      float cmax = 0.f;                            // relu floor
      #pragma unroll
      for (int mt = 0; mt < 4; ++mt)
        #pragma unroll
        for (int ii = 0; ii < 4; ++ii) {
          int s = s0 + mt * 16 + hi * 4 + ii;      // C/D: row=(l>>4)*4+ii, col=l&15
          float v = acc[mt][j][ii] + bia;
          if (s < sval) cmax = fmaxf(cmax, v);
        }
      cmax = fmaxf(cmax, __shfl_xor(cmax, 16));
      cmax = fmaxf(cmax, __shfl_xor(cmax, 32));
      if (hi == 0)
        atomicMax((int*)&feats[b * 300 + f], __float_as_int(fmaxf(cmax, 0.f)));
    }
  }
}

// Block = (sample, s-half): M=64, N=304, K=1600. 4 waves, wave = 4M x 5N (wn3: 4N).
// A staged once in LDS (stride-656, swizzle-free); B global->reg dbuf; barrier-free
// K-loop; 2 blocks/CU so the 2 waves/SIMD come from different blocks (de-phased).
__global__ __launch_bounds__(256, 2)
void conv_max_kernel(const float* __restrict__ x, const u16* __restrict__ wu,
                     const float* __restrict__ b3, const float* __restrict__ b4,
                     const float* __restrict__ b5, float* __restrict__ feats) {
  __shared__ __align__(16) char xs[A_BYTES];
  const int bid = blockIdx.x;
  const int b = bid >> 1, s0 = (bid & 1) * 64;
  const int tid = threadIdx.x;
  const int l = tid & 63, w = tid >> 6;
  const float* xb = x + (size_t)b * (SEQ * EMB);
  const char*  wB = (const char*)wu;

  // stage A: rows s0-2 .. s0+65 (68), cols 0..319 bf16, row stride 656 B
  for (int t = tid; t < 68 * 80; t += 256) {
    int r = t / 80, cg = t - r * 80;
    int xr = s0 - 2 + r;
    float4 v = make_float4(0.f, 0.f, 0.f, 0.f);
    if (xr >= 0 && xr < SEQ && cg < 75)
      v = *reinterpret_cast<const float4*>(xb + xr * EMB + cg * 4);
    ushort4 h;
    h.x = f2bf(v.x); h.y = f2bf(v.y); h.z = f2bf(v.z); h.w = f2bf(v.w);
    *reinterpret_cast<ushort4*>(xs + r * AROW + cg * 8) = h;
  }
  __syncthreads();   // the only barrier: A visible to all 4 waves

  if (w == 3) kloop_epi<4>(xs, wB, 15, l, b, s0, b3, b4, b5, feats);
  else        kloop_epi<5>(xs, wB, w * 5, l, b, s0, b3, b4, b5, feats);
}

// feats[512,300] @ Wfc[5,300]^T + bfc -> log_softmax. One wave per row.
__global__ void fc_kernel(const float* __restrict__ feats, const float* __restrict__ Wfc,
                          const float* __restrict__ bfc, float* __restrict__ out) {
  const int b = blockIdx.x, l = threadIdx.x;
  float acc[5] = {0.f, 0.f, 0.f, 0.f, 0.f};
  for (int e = l; e < 300; e += 64) {
    float fv = feats[b * 300 + e];
    #pragma unroll
    for (int c = 0; c < 5; ++c) acc[c] += fv * Wfc[c * 300 + e];
  }
  #pragma unroll
  for (int off = 32; off; off >>= 1) {
    #pragma unroll
    for (int c = 0; c < 5; ++c) acc[c] += __shfl_down(acc[c], off);
  }
  if (l == 0) {
    float lg[5], m = -1e30f;
    #pragma unroll
    for (int c = 0; c < 5; ++c) { lg[c] = acc[c] + bfc[c]; m = fmaxf(m, lg[c]); }
    float se = 0.f;
    #pragma unroll
    for (int c = 0; c < 5; ++c) se += expf(lg[c] - m);
    float ls = logf(se);
    #pragma unroll
    for (int c = 0; c < 5; ++c) out[b * 5 + c] = lg[c] - m - ls;
  }
}

extern "C" void kernel_launch(void* const* d_in, const int* in_sizes, int n_in,
                              void* d_out, int out_size, void* d_ws, size_t ws_size,
                              hipStream_t stream) {
  const float* x   = (const float*)d_in[0];
  const float* w3  = (const float*)d_in[1];
  const float* b3  = (const float*)d_in[2];
  const float* w4  = (const float*)d_in[3];
  const float* b4  = (const float*)d_in[4];
  const float* w5  = (const float*)d_in[5];
  const float* b5  = (const float*)d_in[6];
  const float* Wfc = (const float*)d_in[7];
  const float* bfc = (const float*)d_in[8];
  float* out = (float*)d_out;

  u16*   wu    = (u16*)d_ws;
  float* feats = (float*)((char*)d_ws + OFF_FEATS);

  hipMemsetAsync(feats, 0, NB * 300 * sizeof(float), stream);  // atomicMax target

  prep_weights<<<(WU_ELEMS + 255) / 256, 256, 0, stream>>>(w3, w4, w5, wu);
  conv_max_kernel<<<NB * 2, 256, 0, stream>>>(x, wu, b3, b4, b5, feats);
  fc_kernel<<<NB, 64, 0, stream>>>(feats, Wfc, bfc, out);
}